// Round 14
// baseline (4168.450 us; speedup 1.0000x reference)
//
#include <hip/hip_runtime.h>
#include <hip/hip_bf16.h>

typedef __bf16 bf16_t;
typedef __bf16 bf16x8 __attribute__((ext_vector_type(8)));
typedef float f32x4 __attribute__((ext_vector_type(4)));

#define GLOAD16(gp, lp) __builtin_amdgcn_global_load_lds(                      \
    (const __attribute__((address_space(1))) void*)(gp),                       \
    (__attribute__((address_space(3))) void*)(lp), 16, 0, 0)
#define BARRIER() asm volatile("s_barrier" ::: "memory")
#define VMC(n) asm volatile("s_waitcnt vmcnt(" #n ")" ::: "memory")
#define LGK0()                                                                 \
  do {                                                                         \
    asm volatile("s_waitcnt lgkmcnt(0)" ::: "memory");                         \
    __builtin_amdgcn_sched_barrier(0);                                         \
  } while (0)

// -------- fused fp32 -> bf16 casts (6 segments, one launch) --------
__global__ __launch_bounds__(256) void cast_all_k(
    const float* __restrict__ x, bf16_t* __restrict__ xb,
    const float* __restrict__ mw, bf16_t* __restrict__ mwb,
    const float* __restrict__ tw, bf16_t* __restrict__ twb,
    const float* __restrict__ pw, bf16_t* __restrict__ pwb,
    const float* __restrict__ gw, bf16_t* __restrict__ gwb,
    const float* __restrict__ Ww, bf16_t* __restrict__ Wwb) {
  const long NB = 2097152;   // 8192*2048/8
  const long WB = 262144;    // 1024*2048/8
  const long total = 2 * NB + 4 * WB;
  long i = (long)blockIdx.x * blockDim.x + threadIdx.x;
  long stride = (long)gridDim.x * blockDim.x;
  for (; i < total; i += stride) {
    const float* src;
    bf16_t* dst;
    long off;
    if (i < NB) {
      src = x; dst = xb; off = i;
    } else if (i < 2 * NB) {
      src = mw; dst = mwb; off = i - NB;
    } else {
      long j = i - 2 * NB;
      int seg = (int)(j >> 18);
      off = j & (WB - 1);
      src = (seg == 0) ? tw : (seg == 1) ? pw : (seg == 2) ? gw : Ww;
      dst = (seg == 0) ? twb : (seg == 1) ? pwb : (seg == 2) ? gwb : Wwb;
    }
    long e = off * 8;
    float4 a = *(const float4*)(src + e);
    float4 b = *(const float4*)(src + e + 4);
    bf16x8 o;
    o[0] = (__bf16)a.x; o[1] = (__bf16)a.y; o[2] = (__bf16)a.z; o[3] = (__bf16)a.w;
    o[4] = (__bf16)b.x; o[5] = (__bf16)b.y; o[6] = (__bf16)b.z; o[7] = (__bf16)b.w;
    *(bf16x8*)(dst + e) = o;
  }
}

// ============ 256x256-tile 8-wave GEMM, BK=64, A-in-LDS / B-DIRECT-to-reg ==
// DS-work reduction: B operand is loaded global->register (L2-hit, issued one
// full K-tile ahead, double-buffered bE/bO), eliminating 64 B-ds_reads + 32KB
// B-staging per K-tile. DS work ~1800cyc < MFMA 2480cyc -> MFMA-bound.
// LDS: 2 x 32KB A buffers. A staging via global_load_lds, slot ^= row&7,
// inverse-swizzled source. 1 barrier + 1 vmcnt(0) per K-tile, 2 lgkm0 phases.
template <int BIAS, bool EMASK, bool RES, bool OUTBF16>
__global__ __launch_bounds__(512, 2) void gemm256(
    const bf16_t* __restrict__ A, long lda, const bf16_t* __restrict__ B,
    long ldb, const float* __restrict__ bias, const bf16_t* __restrict__ ml,
    const float* __restrict__ mrow, const float* __restrict__ invrow,
    const float* __restrict__ res, float* __restrict__ outf,
    bf16_t* __restrict__ outb, int M, int N, int K) {
  __shared__ __align__(1024) char lds[65536];
  const int tid = threadIdx.x;
  const int gx = N >> 8;
  int bid = blockIdx.y * gx + blockIdx.x;
  const int nwg = gridDim.x * gridDim.y;  // multiple of 8 for our shapes
  const int cpx = nwg >> 3;
  bid = (bid & 7) * cpx + (bid >> 3);     // XCD-aware bijective swizzle
  const long row0 = (long)(bid / gx) * 256;
  const long col0 = (long)(bid % gx) * 256;

  const int w = tid >> 6, lane = tid & 63;
  const int wm = w >> 2, wn = w & 3;      // 2M x 4N waves
  const int fr = lane & 15, fq = lane >> 4;

  // A read side: row stride 128B; 16B slot (kk*4+fq) ^ (fr&7)
  const int arow = (wm * 128 + fr) * 128;
  const int sw0 = ((fq ^ (fr & 7)) << 4);
  const int sw1 = (((4 | fq) ^ (fr & 7)) << 4);

  // A staging: thread covers phys bytes tid*16 / +8192 of each 16KB half;
  // row r0 = tid>>3; source k-chunk = (tid&7) ^ (r0&7)
  const int r0 = tid >> 3;
  const int s0 = (tid & 7) ^ (r0 & 7);
  const bf16_t* Ap = A + (row0 + r0) * lda + s0 * 8;
  const int dstA = w * 1024;

  // B direct per-lane base: row = col0 + wn*64 + fr, k-offset fq*8
  const bf16_t* Bg = B + (col0 + wn * 64 + fr) * ldb + fq * 8;

#define STG_A(h, U)                                                            \
  {                                                                            \
    const bf16_t* s_ = Ap + (long)(h)*128 * lda + (long)(U)*64;                \
    char* d_ = lds + (((U)&1) * 32768) + (h)*16384 + dstA;                     \
    GLOAD16(s_, d_);                                                           \
    GLOAD16(s_ + 64 * lda, d_ + 8192);                                         \
  }
#define RD_A(buf, s)                                                           \
  {                                                                            \
    _Pragma("unroll") for (int i = 0; i < 4; ++i) {                            \
      aS[i * 2] = *(const bf16x8*)((buf) + arow + ((s)*4 + i) * 2048 + sw0);   \
      aS[i * 2 + 1] =                                                          \
          *(const bf16x8*)((buf) + arow + ((s)*4 + i) * 2048 + sw1);           \
    }                                                                          \
  }
// load all 8 B fragments of K-tile U into dst[8] (global, L2-hit)
#define LDB(dst, U)                                                            \
  {                                                                            \
    _Pragma("unroll") for (int j = 0; j < 4; ++j)                              \
        _Pragma("unroll") for (int kk = 0; kk < 2; ++kk)                       \
            dst[j * 2 + kk] = *(const bf16x8*)(Bg + (long)j * 16 * ldb +       \
                                               (long)(U)*64 + kk * 32);        \
  }
#define QUAD(BV, I0, J0)                                                       \
  {                                                                            \
    __builtin_amdgcn_s_setprio(1);                                             \
    _Pragma("unroll") for (int i = 0; i < 4; ++i)                              \
        _Pragma("unroll") for (int j = 0; j < 2; ++j)                          \
            _Pragma("unroll") for (int kk = 0; kk < 2; ++kk)                   \
                acc[I0 + i][J0 + j] = __builtin_amdgcn_mfma_f32_16x16x32_bf16( \
                    aS[i * 2 + kk], (BV)[j * 2 + kk], acc[I0 + i][J0 + j], 0,  \
                    0, 0);                                                     \
    __builtin_amdgcn_s_setprio(0);                                             \
  }
#define TILE_BODY(BV)                                                          \
  {                                                                            \
    RD_A(buf, 0);                                                              \
    LGK0();                                                                    \
    QUAD(BV, 0, 0);                                                            \
    QUAD((BV) + 4, 0, 2);                                                      \
    RD_A(buf, 1);                                                              \
    LGK0();                                                                    \
    QUAD((BV) + 4, 4, 2);                                                      \
    QUAD(BV, 4, 0);                                                            \
  }

  f32x4 acc[8][4] = {};
  bf16x8 aS[8], bE[8], bO[8];
  const int NT = K >> 6;  // even, >= 2

  // prologue: stage A tile 0; load B(0) into bE
  STG_A(0, 0); STG_A(1, 0);
  LDB(bE, 0);

  for (int T = 0; T < NT; T += 2) {
    // even tile: consume bE, prefetch bO
    {
      char* buf = lds;
      const bool ST = (T < NT - 1);
      VMC(0);
      BARRIER();
      if (ST) {
        STG_A(0, T + 1); STG_A(1, T + 1);
        LDB(bO, T + 1);
      }
      TILE_BODY(bE);
    }
    if (T + 1 >= NT) break;
    // odd tile: consume bO, prefetch bE
    {
      char* buf = lds + 32768;
      const bool ST = (T + 1 < NT - 1);
      VMC(0);
      BARRIER();
      if (ST) {
        STG_A(0, T + 2); STG_A(1, T + 2);
        LDB(bE, T + 2);
      }
      TILE_BODY(bO);
    }
  }
#undef STG_A
#undef RD_A
#undef LDB
#undef QUAD
#undef TILE_BODY

  // epilogue: C/D layout col=lane&15, row=(lane>>4)*4+r
#pragma unroll
  for (int i = 0; i < 8; ++i)
#pragma unroll
    for (int j = 0; j < 4; ++j)
#pragma unroll
      for (int r = 0; r < 4; ++r) {
        long gi = row0 + wm * 128 + i * 16 + fq * 4 + r;
        long gj = col0 + wn * 64 + j * 16 + fr;
        float v = acc[i][j][r];
        if (BIAS == 1) v += bias[gj];
        long idx = gi * (long)N + gj;
        if (EMASK) v *= __expf((float)ml[idx] - mrow[gi]) * invrow[gi];
        if (RES) v += res[idx];
        if (OUTBF16) outb[idx] = (bf16_t)v;
        else outf[idx] = v;
      }
}

// ============ 256-row x 128-col tile 8-wave GEMM, BK=64 ====================
// Grid (N/128, M/256), 256 blocks = exact fill for our shapes. Waves: 4Mx2N,
// per-wave 64x64 out. LDS: 2 x 48KB {A 256x128B, B 128x128B}. BIAS: 0 none,
// 2 per-row bias[gi].
template <int BIAS>
__global__ __launch_bounds__(512, 2) void gemmT128(
    const bf16_t* __restrict__ A, long lda, const bf16_t* __restrict__ B,
    long ldb, const float* __restrict__ bias, bf16_t* __restrict__ out,
    int M, int N, int K) {
  __shared__ __align__(1024) char lds[98304];
  const int tid = threadIdx.x;
  const int gx = N >> 7;
  int bid = blockIdx.y * gx + blockIdx.x;
  const int nwg = gridDim.x * gridDim.y;  // multiple of 8
  const int cpx = nwg >> 3;
  bid = (bid & 7) * cpx + (bid >> 3);     // XCD-aware bijective swizzle
  const long row0 = (long)(bid / gx) * 256;
  const long col0 = (long)(bid % gx) * 128;

  const int w = tid >> 6, lane = tid & 63;
  const int wm = w >> 1, wn = w & 1;      // 4M x 2N waves
  const int fr = lane & 15, fq = lane >> 4;

  const int arow = (wm * 64 + fr) * 128;
  const int brow = 32768 + (wn * 64 + fr) * 128;
  const int sw0 = ((fq ^ (fr & 7)) << 4);
  const int sw1 = (((4 | fq) ^ (fr & 7)) << 4);

  const int r0 = tid >> 3;
  const int s0 = (tid & 7) ^ (r0 & 7);
  const bf16_t* Ap = A + (row0 + r0) * lda + s0 * 8;
  const bf16_t* Bp = B + (col0 + r0) * ldb + s0 * 8;
  const int dstA = w * 1024;

#define STG_A(U)                                                               \
  {                                                                            \
    char* d_ = lds + (((U)&1) * 49152) + dstA;                                 \
    const bf16_t* s_ = Ap + (long)(U)*64;                                      \
    GLOAD16(s_, d_);                                                           \
    GLOAD16(s_ + 64 * lda, d_ + 8192);                                         \
    GLOAD16(s_ + 128 * lda, d_ + 16384);                                       \
    GLOAD16(s_ + 192 * lda, d_ + 24576);                                       \
  }
#define STG_B(U)                                                               \
  {                                                                            \
    char* d_ = lds + (((U)&1) * 49152) + 32768 + dstA;                         \
    const bf16_t* s_ = Bp + (long)(U)*64;                                      \
    GLOAD16(s_, d_);                                                           \
    GLOAD16(s_ + 64 * ldb, d_ + 8192);                                         \
  }
#define RD_A(buf)                                                              \
  {                                                                            \
    _Pragma("unroll") for (int i = 0; i < 4; ++i) {                            \
      aS[i * 2] = *(const bf16x8*)((buf) + arow + i * 2048 + sw0);             \
      aS[i * 2 + 1] = *(const bf16x8*)((buf) + arow + i * 2048 + sw1);         \
    }                                                                          \
  }
#define RD_B(dst, buf, s)                                                      \
  {                                                                            \
    _Pragma("unroll") for (int j = 0; j < 2; ++j) {                            \
      dst[j * 2] = *(const bf16x8*)((buf) + brow + ((s)*2 + j) * 2048 + sw0);  \
      dst[j * 2 + 1] =                                                         \
          *(const bf16x8*)((buf) + brow + ((s)*2 + j) * 2048 + sw1);           \
    }                                                                          \
  }
#define QUAD(BV, J0)                                                           \
  {                                                                            \
    __builtin_amdgcn_s_setprio(1);                                             \
    _Pragma("unroll") for (int i = 0; i < 4; ++i)                              \
        _Pragma("unroll") for (int j = 0; j < 2; ++j)                          \
            _Pragma("unroll") for (int kk = 0; kk < 2; ++kk)                   \
                acc[i][J0 + j] = __builtin_amdgcn_mfma_f32_16x16x32_bf16(      \
                    aS[i * 2 + kk], BV[j * 2 + kk], acc[i][J0 + j], 0, 0, 0);  \
    __builtin_amdgcn_s_setprio(0);                                             \
  }

  f32x4 acc[4][4] = {};
  bf16x8 aS[8], bA[4], bB[4];
  const int NT = K >> 6;  // >= 2

  STG_A(0); STG_B(0);

  for (int T = 0; T < NT; ++T) {
    char* buf = lds + (T & 1) * 49152;
    const bool ST = (T < NT - 1);
    VMC(0);
    BARRIER();
    if (ST) STG_A(T + 1);
    RD_A(buf);
    RD_B(bA, buf, 0);
    LGK0();
    QUAD(bA, 0);
    RD_B(bB, buf, 1);
    if (ST) STG_B(T + 1);
    LGK0();
    QUAD(bB, 2);
  }
#undef STG_A
#undef STG_B
#undef RD_A
#undef RD_B
#undef QUAD

#pragma unroll
  for (int i = 0; i < 4; ++i)
#pragma unroll
    for (int j = 0; j < 4; ++j)
#pragma unroll
      for (int r = 0; r < 4; ++r) {
        long gi = row0 + wm * 64 + i * 16 + fq * 4 + r;
        long gj = col0 + wn * 64 + j * 16 + fr;
        float v = acc[i][j][r];
        if (BIAS == 2) v += bias[gi];
        out[gi * (long)N + gj] = (bf16_t)v;
      }
}

// ------- row softmax stats over 8192 cols: write per-row max and 1/sum ----
__global__ __launch_bounds__(256) void softmax_stats(
    const bf16_t* __restrict__ buf, float* __restrict__ mrow,
    float* __restrict__ invrow) {
  const long row = blockIdx.x;
  const bf16_t* p = buf + row * 8192;
  const int t = threadIdx.x;
  float v[32];
#pragma unroll
  for (int i = 0; i < 4; i++) {
    bf16x8 raw = *(const bf16x8*)(p + t * 32 + i * 8);
#pragma unroll
    for (int j = 0; j < 8; j++) v[i * 8 + j] = (float)raw[j];
  }
  float m = -1e30f;
#pragma unroll
  for (int i = 0; i < 32; i++) m = fmaxf(m, v[i]);
  for (int off = 32; off; off >>= 1) m = fmaxf(m, __shfl_xor(m, off, 64));
  __shared__ float redm[4], reds[4];
  if ((t & 63) == 0) redm[t >> 6] = m;
  __syncthreads();
  m = fmaxf(fmaxf(redm[0], redm[1]), fmaxf(redm[2], redm[3]));
  float s = 0.f;
#pragma unroll
  for (int i = 0; i < 32; i++) s += __expf(v[i] - m);
  for (int off = 32; off; off >>= 1) s += __shfl_xor(s, off, 64);
  if ((t & 63) == 0) reds[t >> 6] = s;
  __syncthreads();
  if (t == 0) {
    s = reds[0] + reds[1] + reds[2] + reds[3];
    mrow[row] = m;
    invrow[row] = 1.0f / s;
  }
}

// --------- row softmax: bf16 logits in, fp32 out + bf16 in-place ----------
__global__ __launch_bounds__(256) void softmax_f_k(bf16_t* __restrict__ fm,
                                                   float* __restrict__ outf) {
  const long row = blockIdx.x;
  bf16_t* p = fm + row * 8192;
  float* q = outf + row * 8192;
  const int t = threadIdx.x;
  float v[32];
#pragma unroll
  for (int i = 0; i < 4; i++) {
    bf16x8 raw = *(const bf16x8*)(p + t * 32 + i * 8);
#pragma unroll
    for (int j = 0; j < 8; j++) v[i * 8 + j] = (float)raw[j];
  }
  float m = -1e30f;
#pragma unroll
  for (int i = 0; i < 32; i++) m = fmaxf(m, v[i]);
  for (int off = 32; off; off >>= 1) m = fmaxf(m, __shfl_xor(m, off, 64));
  __shared__ float redm[4], reds[4];
  if ((t & 63) == 0) redm[t >> 6] = m;
  __syncthreads();
  m = fmaxf(fmaxf(redm[0], redm[1]), fmaxf(redm[2], redm[3]));
  float s = 0.f;
#pragma unroll
  for (int i = 0; i < 32; i++) {
    v[i] = __expf(v[i] - m);
    s += v[i];
  }
  for (int off = 32; off; off >>= 1) s += __shfl_xor(s, off, 64);
  if ((t & 63) == 0) reds[t >> 6] = s;
  __syncthreads();
  s = reds[0] + reds[1] + reds[2] + reds[3];
  float inv = 1.0f / s;
#pragma unroll
  for (int i = 0; i < 8; i++) {
    float4 o;
    o.x = v[i * 4 + 0] * inv;
    o.y = v[i * 4 + 1] * inv;
    o.z = v[i * 4 + 2] * inv;
    o.w = v[i * 4 + 3] * inv;
    *(float4*)(q + t * 32 + i * 4) = o;
  }
#pragma unroll
  for (int i = 0; i < 4; i++) {
    bf16x8 o;
#pragma unroll
    for (int j = 0; j < 8; j++) o[j] = (bf16_t)(v[i * 8 + j] * inv);
    *(bf16x8*)(p + t * 32 + i * 8) = o;
  }
}

// ---------------------------------------------------------------------------
extern "C" void kernel_launch(void* const* d_in, const int* in_sizes, int n_in,
                              void* d_out, int out_size, void* d_ws,
                              size_t ws_size, hipStream_t stream) {
  const int N = 8192, C = 2048, IC = 1024;
  const float* x = (const float*)d_in[0];
  const float* theta_w = (const float*)d_in[1];
  const float* theta_b = (const float*)d_in[2];
  const float* phi_w = (const float*)d_in[3];
  const float* phi_b = (const float*)d_in[4];
  const float* g_w = (const float*)d_in[5];
  const float* g_b = (const float*)d_in[6];
  const float* W_w = (const float*)d_in[7];
  const float* W_b = (const float*)d_in[8];
  const float* mask_w = (const float*)d_in[9];
  const float* mask_b = (const float*)d_in[10];

  float* z_out = (float*)d_out;            // [N,C] fp32
  float* f_out = z_out + (long)N * C;      // [N,N] fp32

  bf16_t* ML = (bf16_t*)f_out;             // [N,N] bf16 raw mask logits
  bf16_t* thph16 = (bf16_t*)z_out;         // [N,2048]: theta | phi
  bf16_t* gT16 = thph16 + (long)N * 2048;  // [IC,N]

  char* w = (char*)d_ws;
  bf16_t* xb = (bf16_t*)w;      w += (long)N * C * 2;
  bf16_t* mwb = (bf16_t*)w;     w += (long)N * C * 2;
  bf16_t* thwb = (bf16_t*)w;    w += (long)IC * C * 2;
  bf16_t* phwb = (bf16_t*)w;    w += (long)IC * C * 2;
  bf16_t* gwb = (bf16_t*)w;     w += (long)IC * C * 2;
  bf16_t* Wwb = (bf16_t*)w;     w += (long)C * IC * 2;
  bf16_t* fm = (bf16_t*)w;      w += (long)N * N * 2;
  bf16_t* y16 = (bf16_t*)w;     w += (long)N * IC * 2;
  float* mrowb = (float*)w;     w += (long)N * 4;
  float* invrowb = (float*)w;   w += (long)N * 4;
  float* thph_b = (float*)w;    w += (long)2 * IC * 4;

  cast_all_k<<<4096, 256, 0, stream>>>(x, xb, mask_w, mwb, theta_w, thwb,
                                       phi_w, phwb, g_w, gwb, W_w, Wwb);
  hipMemcpyAsync(thph_b, theta_b, IC * 4, hipMemcpyDeviceToDevice, stream);
  hipMemcpyAsync(thph_b + IC, phi_b, IC * 4, hipMemcpyDeviceToDevice, stream);

  // theta+phi merged projection: [8192,2048] = xb @ [thwb;phwb]^T + bias
  gemm256<1, false, false, true><<<dim3(2048 / 256, N / 256), 512, 0, stream>>>(
      xb, C, thwb, C, thph_b, nullptr, nullptr, nullptr, nullptr, nullptr,
      thph16, N, 2048, C);
  // g_x^T : [IC,N] = g_w @ xb^T + g_b (row bias), 256x128-tile, 256 blocks
  gemmT128<2><<<dim3(N / 128, IC / 256), 512, 0, stream>>>(
      gwb, C, xb, C, g_b, gT16, IC, N, C);
  // mask logits -> raw ML (bias per col)
  gemm256<1, false, false, true><<<dim3(N / 256, N / 256), 512, 0, stream>>>(
      xb, C, mwb, C, mask_b, nullptr, nullptr, nullptr, nullptr, nullptr,
      ML, N, N, C);
  // mask softmax stats only (read-only pass)
  softmax_stats<<<N, 256, 0, stream>>>(ML, mrowb, invrowb);
  // f*mask logits: theta_x @ phi_x^T with folded exp-mask epilogue
  gemm256<0, true, false, true><<<dim3(N / 256, N / 256), 512, 0, stream>>>(
      thph16, 2048, thph16 + 1024, 2048, nullptr, ML, mrowb, invrowb,
      nullptr, nullptr, fm, N, N, IC);
  softmax_f_k<<<N, 256, 0, stream>>>(fm, f_out);
  // y = P @ g_x (NT via gT16), 256x128-tile kernel, exact 256-block fill
  gemmT128<0><<<dim3(IC / 128, N / 256), 512, 0, stream>>>(
      fm, N, gT16, N, nullptr, y16, N, IC, N);
  // z = y @ W_w^T + W_b + x (256^2 kernel, fp32 out + residual)
  gemm256<1, false, true, false><<<dim3(C / 256, N / 256), 512, 0, stream>>>(
      y16, IC, Wwb, IC, W_b, nullptr, nullptr, nullptr, x, z_out, nullptr,
      N, C, IC);
}

// Round 15
// 943.711 us; speedup vs baseline: 4.4171x; 4.4171x over previous
//
#include <hip/hip_runtime.h>
#include <hip/hip_bf16.h>

typedef __bf16 bf16_t;
typedef __bf16 bf16x8 __attribute__((ext_vector_type(8)));
typedef float f32x4 __attribute__((ext_vector_type(4)));

#define GLOAD16(gp, lp) __builtin_amdgcn_global_load_lds(                      \
    (const __attribute__((address_space(1))) void*)(gp),                       \
    (__attribute__((address_space(3))) void*)(lp), 16, 0, 0)
#define BARRIER() asm volatile("s_barrier" ::: "memory")
#define VMC(n) asm volatile("s_waitcnt vmcnt(" #n ")" ::: "memory")
#define LGK0()                                                                 \
  do {                                                                         \
    asm volatile("s_waitcnt lgkmcnt(0)" ::: "memory");                         \
    __builtin_amdgcn_sched_barrier(0);                                         \
  } while (0)

// -------- fused fp32 -> bf16 casts (6 segments, one launch) --------
__global__ __launch_bounds__(256) void cast_all_k(
    const float* __restrict__ x, bf16_t* __restrict__ xb,
    const float* __restrict__ mw, bf16_t* __restrict__ mwb,
    const float* __restrict__ tw, bf16_t* __restrict__ twb,
    const float* __restrict__ pw, bf16_t* __restrict__ pwb,
    const float* __restrict__ gw, bf16_t* __restrict__ gwb,
    const float* __restrict__ Ww, bf16_t* __restrict__ Wwb) {
  const long NB = 2097152;   // 8192*2048/8
  const long WB = 262144;    // 1024*2048/8
  const long total = 2 * NB + 4 * WB;
  long i = (long)blockIdx.x * blockDim.x + threadIdx.x;
  long stride = (long)gridDim.x * blockDim.x;
  for (; i < total; i += stride) {
    const float* src;
    bf16_t* dst;
    long off;
    if (i < NB) {
      src = x; dst = xb; off = i;
    } else if (i < 2 * NB) {
      src = mw; dst = mwb; off = i - NB;
    } else {
      long j = i - 2 * NB;
      int seg = (int)(j >> 18);
      off = j & (WB - 1);
      src = (seg == 0) ? tw : (seg == 1) ? pw : (seg == 2) ? gw : Ww;
      dst = (seg == 0) ? twb : (seg == 1) ? pwb : (seg == 2) ? gwb : Wwb;
    }
    long e = off * 8;
    float4 a = *(const float4*)(src + e);
    float4 b = *(const float4*)(src + e + 4);
    bf16x8 o;
    o[0] = (__bf16)a.x; o[1] = (__bf16)a.y; o[2] = (__bf16)a.z; o[3] = (__bf16)a.w;
    o[4] = (__bf16)b.x; o[5] = (__bf16)b.y; o[6] = (__bf16)b.z; o[7] = (__bf16)b.w;
    *(bf16x8*)(dst + e) = o;
  }
}

// ============ 256x256-tile 8-wave GEMM, BK=64, 1 barrier / 1 vmcnt per
// K-tile (round-8/13 measured-best body). 4 quadrant-phases: same-phase
// lgkm(0), no mid-tile barriers. LDS: 2 x 64KB buffers {A 256x128B,
// B 256x128B}. 16B slot ^= (row&7); staging inverse-swizzles the global
// source (linear LDS dest). A/B have independent row strides lda/ldb.
template <int BIAS, bool EMASK, bool RES, bool OUTBF16>
__global__ __launch_bounds__(512, 2) void gemm256(
    const bf16_t* __restrict__ A, long lda, const bf16_t* __restrict__ B,
    long ldb, const float* __restrict__ bias, const bf16_t* __restrict__ ml,
    const float* __restrict__ mrow, const float* __restrict__ invrow,
    const float* __restrict__ res, float* __restrict__ outf,
    bf16_t* __restrict__ outb, int M, int N, int K) {
  __shared__ __align__(1024) char lds[131072];
  const int tid = threadIdx.x;
  const int gx = N >> 8;
  int bid = blockIdx.y * gx + blockIdx.x;
  const int nwg = gridDim.x * gridDim.y;  // multiple of 8 for our shapes
  const int cpx = nwg >> 3;
  bid = (bid & 7) * cpx + (bid >> 3);     // XCD-aware bijective swizzle
  const long row0 = (long)(bid / gx) * 256;
  const long col0 = (long)(bid % gx) * 256;

  const int w = tid >> 6, lane = tid & 63;
  const int wm = w >> 2, wn = w & 3;      // 2M x 4N waves
  const int fr = lane & 15, fq = lane >> 4;

  const int arow = (wm * 128 + fr) * 128;
  const int brow = 32768 + (wn * 64 + fr) * 128;
  const int sw0 = ((fq ^ (fr & 7)) << 4);
  const int sw1 = (((4 | fq) ^ (fr & 7)) << 4);

  const int r0 = tid >> 3;
  const int s0 = (tid & 7) ^ (r0 & 7);
  const bf16_t* Ap = A + (row0 + r0) * lda + s0 * 8;
  const bf16_t* Bp = B + (col0 + r0) * ldb + s0 * 8;
  const int dstA = w * 1024;

#define STG_A(h, U)                                                            \
  {                                                                            \
    const bf16_t* s_ = Ap + (long)(h)*128 * lda + (long)(U)*64;                \
    char* d_ = lds + (((U)&1) * 65536) + (h)*16384 + dstA;                     \
    GLOAD16(s_, d_);                                                           \
    GLOAD16(s_ + 64 * lda, d_ + 8192);                                         \
  }
#define STG_B(h, U)                                                            \
  {                                                                            \
    const bf16_t* s_ = Bp + (long)(h)*128 * ldb + (long)(U)*64;                \
    char* d_ = lds + (((U)&1) * 65536) + 32768 + (h)*16384 + dstA;             \
    GLOAD16(s_, d_);                                                           \
    GLOAD16(s_ + 64 * ldb, d_ + 8192);                                         \
  }
#define RD_A(buf, s)                                                           \
  {                                                                            \
    _Pragma("unroll") for (int i = 0; i < 4; ++i) {                            \
      aS[i * 2] = *(const bf16x8*)((buf) + arow + ((s)*4 + i) * 2048 + sw0);   \
      aS[i * 2 + 1] =                                                          \
          *(const bf16x8*)((buf) + arow + ((s)*4 + i) * 2048 + sw1);           \
    }                                                                          \
  }
#define RD_B(dst, buf, s)                                                      \
  {                                                                            \
    _Pragma("unroll") for (int j = 0; j < 2; ++j) {                            \
      dst[j * 2] = *(const bf16x8*)((buf) + brow + ((s)*2 + j) * 2048 + sw0);  \
      dst[j * 2 + 1] =                                                         \
          *(const bf16x8*)((buf) + brow + ((s)*2 + j) * 2048 + sw1);           \
    }                                                                          \
  }
#define QUAD(BV, I0, J0)                                                       \
  {                                                                            \
    __builtin_amdgcn_s_setprio(1);                                             \
    _Pragma("unroll") for (int i = 0; i < 4; ++i)                              \
        _Pragma("unroll") for (int j = 0; j < 2; ++j)                          \
            _Pragma("unroll") for (int kk = 0; kk < 2; ++kk)                   \
                acc[I0 + i][J0 + j] = __builtin_amdgcn_mfma_f32_16x16x32_bf16( \
                    aS[i * 2 + kk], BV[j * 2 + kk], acc[I0 + i][J0 + j], 0, 0, \
                    0);                                                        \
    __builtin_amdgcn_s_setprio(0);                                             \
  }

  f32x4 acc[8][4] = {};
  bf16x8 aS[8], bA[4], bB[4];
  const int NT = K >> 6;  // >= 2

  STG_A(0, 0); STG_A(1, 0); STG_B(0, 0); STG_B(1, 0);

  for (int T = 0; T < NT; ++T) {
    char* buf = lds + (T & 1) * 65536;
    const bool ST = (T < NT - 1);
    VMC(0);
    BARRIER();
    if (ST) STG_A(0, T + 1);
    RD_A(buf, 0);
    RD_B(bA, buf, 0);
    LGK0();
    QUAD(bA, 0, 0);
    RD_B(bB, buf, 1);
    if (ST) STG_A(1, T + 1);
    LGK0();
    QUAD(bB, 0, 2);
    RD_A(buf, 1);
    if (ST) STG_B(0, T + 1);
    LGK0();
    QUAD(bB, 4, 2);
    if (ST) STG_B(1, T + 1);
    QUAD(bA, 4, 0);
  }
#undef STG_A
#undef STG_B
#undef RD_A
#undef RD_B
#undef QUAD

#pragma unroll
  for (int i = 0; i < 8; ++i)
#pragma unroll
    for (int j = 0; j < 4; ++j)
#pragma unroll
      for (int r = 0; r < 4; ++r) {
        long gi = row0 + wm * 128 + i * 16 + fq * 4 + r;
        long gj = col0 + wn * 64 + j * 16 + fr;
        float v = acc[i][j][r];
        if (BIAS == 1) v += bias[gj];
        long idx = gi * (long)N + gj;
        if (EMASK) v *= __expf((float)ml[idx] - mrow[gi]) * invrow[gi];
        if (RES) v += res[idx];
        if (OUTBF16) outb[idx] = (bf16_t)v;
        else outf[idx] = v;
      }
}

// ============ 256-row x 128-col tile 8-wave GEMM, BK=64 ====================
// Grid (N/128, M/256), 256 blocks = exact fill for our shapes. Waves: 4Mx2N,
// per-wave 64x64 out. LDS: 2 x 48KB {A 256x128B, B 128x128B}. BIAS: 0 none,
// 2 per-row bias[gi].
template <int BIAS>
__global__ __launch_bounds__(512, 2) void gemmT128(
    const bf16_t* __restrict__ A, long lda, const bf16_t* __restrict__ B,
    long ldb, const float* __restrict__ bias, bf16_t* __restrict__ out,
    int M, int N, int K) {
  __shared__ __align__(1024) char lds[98304];
  const int tid = threadIdx.x;
  const int gx = N >> 7;
  int bid = blockIdx.y * gx + blockIdx.x;
  const int nwg = gridDim.x * gridDim.y;  // multiple of 8
  const int cpx = nwg >> 3;
  bid = (bid & 7) * cpx + (bid >> 3);     // XCD-aware bijective swizzle
  const long row0 = (long)(bid / gx) * 256;
  const long col0 = (long)(bid % gx) * 128;

  const int w = tid >> 6, lane = tid & 63;
  const int wm = w >> 1, wn = w & 1;      // 4M x 2N waves
  const int fr = lane & 15, fq = lane >> 4;

  const int arow = (wm * 64 + fr) * 128;
  const int brow = 32768 + (wn * 64 + fr) * 128;
  const int sw0 = ((fq ^ (fr & 7)) << 4);
  const int sw1 = (((4 | fq) ^ (fr & 7)) << 4);

  const int r0 = tid >> 3;
  const int s0 = (tid & 7) ^ (r0 & 7);
  const bf16_t* Ap = A + (row0 + r0) * lda + s0 * 8;
  const bf16_t* Bp = B + (col0 + r0) * ldb + s0 * 8;
  const int dstA = w * 1024;

#define STG_A(U)                                                               \
  {                                                                            \
    char* d_ = lds + (((U)&1) * 49152) + dstA;                                 \
    const bf16_t* s_ = Ap + (long)(U)*64;                                      \
    GLOAD16(s_, d_);                                                           \
    GLOAD16(s_ + 64 * lda, d_ + 8192);                                         \
    GLOAD16(s_ + 128 * lda, d_ + 16384);                                       \
    GLOAD16(s_ + 192 * lda, d_ + 24576);                                       \
  }
#define STG_B(U)                                                               \
  {                                                                            \
    char* d_ = lds + (((U)&1) * 49152) + 32768 + dstA;                         \
    const bf16_t* s_ = Bp + (long)(U)*64;                                      \
    GLOAD16(s_, d_);                                                           \
    GLOAD16(s_ + 64 * ldb, d_ + 8192);                                         \
  }
#define RD_A(buf)                                                              \
  {                                                                            \
    _Pragma("unroll") for (int i = 0; i < 4; ++i) {                            \
      aS[i * 2] = *(const bf16x8*)((buf) + arow + i * 2048 + sw0);             \
      aS[i * 2 + 1] = *(const bf16x8*)((buf) + arow + i * 2048 + sw1);         \
    }                                                                          \
  }
#define RD_B(dst, buf, s)                                                      \
  {                                                                            \
    _Pragma("unroll") for (int j = 0; j < 2; ++j) {                            \
      dst[j * 2] = *(const bf16x8*)((buf) + brow + ((s)*2 + j) * 2048 + sw0);  \
      dst[j * 2 + 1] =                                                         \
          *(const bf16x8*)((buf) + brow + ((s)*2 + j) * 2048 + sw1);           \
    }                                                                          \
  }
#define QUAD(BV, J0)                                                           \
  {                                                                            \
    __builtin_amdgcn_s_setprio(1);                                             \
    _Pragma("unroll") for (int i = 0; i < 4; ++i)                              \
        _Pragma("unroll") for (int j = 0; j < 2; ++j)                          \
            _Pragma("unroll") for (int kk = 0; kk < 2; ++kk)                   \
                acc[i][J0 + j] = __builtin_amdgcn_mfma_f32_16x16x32_bf16(      \
                    aS[i * 2 + kk], BV[j * 2 + kk], acc[i][J0 + j], 0, 0, 0);  \
    __builtin_amdgcn_s_setprio(0);                                             \
  }

  f32x4 acc[4][4] = {};
  bf16x8 aS[8], bA[4], bB[4];
  const int NT = K >> 6;  // >= 2

  STG_A(0); STG_B(0);

  for (int T = 0; T < NT; ++T) {
    char* buf = lds + (T & 1) * 49152;
    const bool ST = (T < NT - 1);
    VMC(0);
    BARRIER();
    if (ST) STG_A(T + 1);
    RD_A(buf);
    RD_B(bA, buf, 0);
    LGK0();
    QUAD(bA, 0);
    RD_B(bB, buf, 1);
    if (ST) STG_B(T + 1);
    LGK0();
    QUAD(bB, 2);
  }
#undef STG_A
#undef STG_B
#undef RD_A
#undef RD_B
#undef QUAD

#pragma unroll
  for (int i = 0; i < 4; ++i)
#pragma unroll
    for (int j = 0; j < 4; ++j)
#pragma unroll
      for (int r = 0; r < 4; ++r) {
        long gi = row0 + wm * 64 + i * 16 + fq * 4 + r;
        long gj = col0 + wn * 64 + j * 16 + fr;
        float v = acc[i][j][r];
        if (BIAS == 2) v += bias[gi];
        out[gi * (long)N + gj] = (bf16_t)v;
      }
}

// ------- row softmax stats over 8192 cols: write per-row max and 1/sum ----
__global__ __launch_bounds__(256) void softmax_stats(
    const bf16_t* __restrict__ buf, float* __restrict__ mrow,
    float* __restrict__ invrow) {
  const long row = blockIdx.x;
  const bf16_t* p = buf + row * 8192;
  const int t = threadIdx.x;
  float v[32];
#pragma unroll
  for (int i = 0; i < 4; i++) {
    bf16x8 raw = *(const bf16x8*)(p + t * 32 + i * 8);
#pragma unroll
    for (int j = 0; j < 8; j++) v[i * 8 + j] = (float)raw[j];
  }
  float m = -1e30f;
#pragma unroll
  for (int i = 0; i < 32; i++) m = fmaxf(m, v[i]);
  for (int off = 32; off; off >>= 1) m = fmaxf(m, __shfl_xor(m, off, 64));
  __shared__ float redm[4], reds[4];
  if ((t & 63) == 0) redm[t >> 6] = m;
  __syncthreads();
  m = fmaxf(fmaxf(redm[0], redm[1]), fmaxf(redm[2], redm[3]));
  float s = 0.f;
#pragma unroll
  for (int i = 0; i < 32; i++) s += __expf(v[i] - m);
  for (int off = 32; off; off >>= 1) s += __shfl_xor(s, off, 64);
  if ((t & 63) == 0) reds[t >> 6] = s;
  __syncthreads();
  if (t == 0) {
    s = reds[0] + reds[1] + reds[2] + reds[3];
    mrow[row] = m;
    invrow[row] = 1.0f / s;
  }
}

// --------- row softmax: bf16 logits in, fp32 out + bf16 in-place ----------
__global__ __launch_bounds__(256) void softmax_f_k(bf16_t* __restrict__ fm,
                                                   float* __restrict__ outf) {
  const long row = blockIdx.x;
  bf16_t* p = fm + row * 8192;
  float* q = outf + row * 8192;
  const int t = threadIdx.x;
  float v[32];
#pragma unroll
  for (int i = 0; i < 4; i++) {
    bf16x8 raw = *(const bf16x8*)(p + t * 32 + i * 8);
#pragma unroll
    for (int j = 0; j < 8; j++) v[i * 8 + j] = (float)raw[j];
  }
  float m = -1e30f;
#pragma unroll
  for (int i = 0; i < 32; i++) m = fmaxf(m, v[i]);
  for (int off = 32; off; off >>= 1) m = fmaxf(m, __shfl_xor(m, off, 64));
  __shared__ float redm[4], reds[4];
  if ((t & 63) == 0) redm[t >> 6] = m;
  __syncthreads();
  m = fmaxf(fmaxf(redm[0], redm[1]), fmaxf(redm[2], redm[3]));
  float s = 0.f;
#pragma unroll
  for (int i = 0; i < 32; i++) {
    v[i] = __expf(v[i] - m);
    s += v[i];
  }
  for (int off = 32; off; off >>= 1) s += __shfl_xor(s, off, 64);
  if ((t & 63) == 0) reds[t >> 6] = s;
  __syncthreads();
  s = reds[0] + reds[1] + reds[2] + reds[3];
  float inv = 1.0f / s;
#pragma unroll
  for (int i = 0; i < 8; i++) {
    float4 o;
    o.x = v[i * 4 + 0] * inv;
    o.y = v[i * 4 + 1] * inv;
    o.z = v[i * 4 + 2] * inv;
    o.w = v[i * 4 + 3] * inv;
    *(float4*)(q + t * 32 + i * 4) = o;
  }
#pragma unroll
  for (int i = 0; i < 4; i++) {
    bf16x8 o;
#pragma unroll
    for (int j = 0; j < 8; j++) o[j] = (bf16_t)(v[i * 8 + j] * inv);
    *(bf16x8*)(p + t * 32 + i * 8) = o;
  }
}

// ---------------------------------------------------------------------------
extern "C" void kernel_launch(void* const* d_in, const int* in_sizes, int n_in,
                              void* d_out, int out_size, void* d_ws,
                              size_t ws_size, hipStream_t stream) {
  const int N = 8192, C = 2048, IC = 1024;
  const float* x = (const float*)d_in[0];
  const float* theta_w = (const float*)d_in[1];
  const float* theta_b = (const float*)d_in[2];
  const float* phi_w = (const float*)d_in[3];
  const float* phi_b = (const float*)d_in[4];
  const float* g_w = (const float*)d_in[5];
  const float* g_b = (const float*)d_in[6];
  const float* W_w = (const float*)d_in[7];
  const float* W_b = (const float*)d_in[8];
  const float* mask_w = (const float*)d_in[9];
  const float* mask_b = (const float*)d_in[10];

  float* z_out = (float*)d_out;            // [N,C] fp32
  float* f_out = z_out + (long)N * C;      // [N,N] fp32

  bf16_t* ML = (bf16_t*)f_out;             // [N,N] bf16 raw mask logits
  bf16_t* thph16 = (bf16_t*)z_out;         // [N,2048]: theta | phi
  bf16_t* gT16 = thph16 + (long)N * 2048;  // [IC,N]

  char* w = (char*)d_ws;
  bf16_t* xb = (bf16_t*)w;      w += (long)N * C * 2;
  bf16_t* mwb = (bf16_t*)w;     w += (long)N * C * 2;
  bf16_t* thwb = (bf16_t*)w;    w += (long)IC * C * 2;
  bf16_t* phwb = (bf16_t*)w;    w += (long)IC * C * 2;
  bf16_t* gwb = (bf16_t*)w;     w += (long)IC * C * 2;
  bf16_t* Wwb = (bf16_t*)w;     w += (long)C * IC * 2;
  bf16_t* fm = (bf16_t*)w;      w += (long)N * N * 2;
  bf16_t* y16 = (bf16_t*)w;     w += (long)N * IC * 2;
  float* mrowb = (float*)w;     w += (long)N * 4;
  float* invrowb = (float*)w;   w += (long)N * 4;
  float* thph_b = (float*)w;    w += (long)2 * IC * 4;

  cast_all_k<<<4096, 256, 0, stream>>>(x, xb, mask_w, mwb, theta_w, thwb,
                                       phi_w, phwb, g_w, gwb, W_w, Wwb);
  hipMemcpyAsync(thph_b, theta_b, IC * 4, hipMemcpyDeviceToDevice, stream);
  hipMemcpyAsync(thph_b + IC, phi_b, IC * 4, hipMemcpyDeviceToDevice, stream);

  // theta+phi merged projection: [8192,2048] = xb @ [thwb;phwb]^T + bias
  gemm256<1, false, false, true><<<dim3(2048 / 256, N / 256), 512, 0, stream>>>(
      xb, C, thwb, C, thph_b, nullptr, nullptr, nullptr, nullptr, nullptr,
      thph16, N, 2048, C);
  // g_x^T : [IC,N] = g_w @ xb^T + g_b (row bias), 256x128-tile, 256 blocks
  gemmT128<2><<<dim3(N / 128, IC / 256), 512, 0, stream>>>(
      gwb, C, xb, C, g_b, gT16, IC, N, C);
  // mask logits -> raw ML (bias per col)
  gemm256<1, false, false, true><<<dim3(N / 256, N / 256), 512, 0, stream>>>(
      xb, C, mwb, C, mask_b, nullptr, nullptr, nullptr, nullptr, nullptr,
      ML, N, N, C);
  // mask softmax stats only (read-only pass)
  softmax_stats<<<N, 256, 0, stream>>>(ML, mrowb, invrowb);
  // f*mask logits: theta_x @ phi_x^T with folded exp-mask epilogue
  gemm256<0, true, false, true><<<dim3(N / 256, N / 256), 512, 0, stream>>>(
      thph16, 2048, thph16 + 1024, 2048, nullptr, ML, mrowb, invrowb,
      nullptr, nullptr, fm, N, N, IC);
  softmax_f_k<<<N, 256, 0, stream>>>(fm, f_out);
  // y = P @ g_x (NT via gT16), 256x128-tile kernel, exact 256-block fill
  gemmT128<0><<<dim3(IC / 128, N / 256), 512, 0, stream>>>(
      fm, N, gT16, N, nullptr, y16, N, IC, N);
  // z = y @ W_w^T + W_b + x (256^2 kernel, fp32 out + residual)
  gemm256<1, false, true, false><<<dim3(C / 256, N / 256), 512, 0, stream>>>(
      y16, IC, Wwb, IC, W_b, nullptr, nullptr, nullptr, x, z_out, nullptr,
      N, C, IC);
}

// Round 16
// 935.924 us; speedup vs baseline: 4.4538x; 1.0083x over previous
//
#include <hip/hip_runtime.h>
#include <hip/hip_bf16.h>

typedef __bf16 bf16_t;
typedef __bf16 bf16x8 __attribute__((ext_vector_type(8)));
typedef float f32x4 __attribute__((ext_vector_type(4)));

#define GLOAD16(gp, lp) __builtin_amdgcn_global_load_lds(                      \
    (const __attribute__((address_space(1))) void*)(gp),                       \
    (__attribute__((address_space(3))) void*)(lp), 16, 0, 0)
#define BARRIER() asm volatile("s_barrier" ::: "memory")
#define VMC(n) asm volatile("s_waitcnt vmcnt(" #n ")" ::: "memory")
#define LGK0()                                                                 \
  do {                                                                         \
    asm volatile("s_waitcnt lgkmcnt(0)" ::: "memory");                         \
    __builtin_amdgcn_sched_barrier(0);                                         \
  } while (0)

// -------- fused fp32 -> bf16 casts (6 segments, one launch) --------
__global__ __launch_bounds__(256) void cast_all_k(
    const float* __restrict__ x, bf16_t* __restrict__ xb,
    const float* __restrict__ mw, bf16_t* __restrict__ mwb,
    const float* __restrict__ tw, bf16_t* __restrict__ twb,
    const float* __restrict__ pw, bf16_t* __restrict__ pwb,
    const float* __restrict__ gw, bf16_t* __restrict__ gwb,
    const float* __restrict__ Ww, bf16_t* __restrict__ Wwb) {
  const long NB = 2097152;   // 8192*2048/8
  const long WB = 262144;    // 1024*2048/8
  const long total = 2 * NB + 4 * WB;
  long i = (long)blockIdx.x * blockDim.x + threadIdx.x;
  long stride = (long)gridDim.x * blockDim.x;
  for (; i < total; i += stride) {
    const float* src;
    bf16_t* dst;
    long off;
    if (i < NB) {
      src = x; dst = xb; off = i;
    } else if (i < 2 * NB) {
      src = mw; dst = mwb; off = i - NB;
    } else {
      long j = i - 2 * NB;
      int seg = (int)(j >> 18);
      off = j & (WB - 1);
      src = (seg == 0) ? tw : (seg == 1) ? pw : (seg == 2) ? gw : Ww;
      dst = (seg == 0) ? twb : (seg == 1) ? pwb : (seg == 2) ? gwb : Wwb;
    }
    long e = off * 8;
    float4 a = *(const float4*)(src + e);
    float4 b = *(const float4*)(src + e + 4);
    bf16x8 o;
    o[0] = (__bf16)a.x; o[1] = (__bf16)a.y; o[2] = (__bf16)a.z; o[3] = (__bf16)a.w;
    o[4] = (__bf16)b.x; o[5] = (__bf16)b.y; o[6] = (__bf16)b.z; o[7] = (__bf16)b.w;
    *(bf16x8*)(dst + e) = o;
  }
}

// ============ 256x256-tile 8-wave GEMM, BK=64, 1 barrier / 1 vmcnt per
// K-tile. 4 quadrant-phases with WAVE-GROUP PHASE STAGGER: wm=0 waves walk
// quadrants (A0B0,A0B1,A1B1,A1B0); wm=1 waves start from the opposite corner
// (A1B1,A1B0,A0B0,A0B1). Each SIMD hosts one wave of each group, so partner
// waves are half-a-tile out of phase: DS bursts hide under MFMA clusters.
// LDS: 2 x 64KB buffers {A 256x128B, B 256x128B}. 16B slot ^= (row&7);
// staging inverse-swizzles the global source (linear LDS dest).
template <int BIAS, bool EMASK, bool RES, bool OUTBF16>
__global__ __launch_bounds__(512, 2) void gemm256(
    const bf16_t* __restrict__ A, long lda, const bf16_t* __restrict__ B,
    long ldb, const float* __restrict__ bias, const bf16_t* __restrict__ ml,
    const float* __restrict__ mrow, const float* __restrict__ invrow,
    const float* __restrict__ res, float* __restrict__ outf,
    bf16_t* __restrict__ outb, int M, int N, int K) {
  __shared__ __align__(1024) char lds[131072];
  const int tid = threadIdx.x;
  const int gx = N >> 8;
  int bid = blockIdx.y * gx + blockIdx.x;
  const int nwg = gridDim.x * gridDim.y;  // multiple of 8 for our shapes
  const int cpx = nwg >> 3;
  bid = (bid & 7) * cpx + (bid >> 3);     // XCD-aware bijective swizzle
  const long row0 = (long)(bid / gx) * 256;
  const long col0 = (long)(bid % gx) * 256;

  const int w = tid >> 6, lane = tid & 63;
  const int wm = w >> 2, wn = w & 3;      // 2M x 4N waves
  const int fr = lane & 15, fq = lane >> 4;

  const int arow = (wm * 128 + fr) * 128;
  const int brow = 32768 + (wn * 64 + fr) * 128;
  const int sw0 = ((fq ^ (fr & 7)) << 4);
  const int sw1 = (((4 | fq) ^ (fr & 7)) << 4);

  const int r0 = tid >> 3;
  const int s0 = (tid & 7) ^ (r0 & 7);
  const bf16_t* Ap = A + (row0 + r0) * lda + s0 * 8;
  const bf16_t* Bp = B + (col0 + r0) * ldb + s0 * 8;
  const int dstA = w * 1024;

#define STG_A(h, U)                                                            \
  {                                                                            \
    const bf16_t* s_ = Ap + (long)(h)*128 * lda + (long)(U)*64;                \
    char* d_ = lds + (((U)&1) * 65536) + (h)*16384 + dstA;                     \
    GLOAD16(s_, d_);                                                           \
    GLOAD16(s_ + 64 * lda, d_ + 8192);                                         \
  }
#define STG_B(h, U)                                                            \
  {                                                                            \
    const bf16_t* s_ = Bp + (long)(h)*128 * ldb + (long)(U)*64;                \
    char* d_ = lds + (((U)&1) * 65536) + 32768 + (h)*16384 + dstA;             \
    GLOAD16(s_, d_);                                                           \
    GLOAD16(s_ + 64 * ldb, d_ + 8192);                                         \
  }
#define RD_A(buf, s)                                                           \
  {                                                                            \
    _Pragma("unroll") for (int i = 0; i < 4; ++i) {                            \
      aS[i * 2] = *(const bf16x8*)((buf) + arow + ((s)*4 + i) * 2048 + sw0);   \
      aS[i * 2 + 1] =                                                          \
          *(const bf16x8*)((buf) + arow + ((s)*4 + i) * 2048 + sw1);           \
    }                                                                          \
  }
#define RD_B(dst, buf, s)                                                      \
  {                                                                            \
    _Pragma("unroll") for (int j = 0; j < 2; ++j) {                            \
      dst[j * 2] = *(const bf16x8*)((buf) + brow + ((s)*2 + j) * 2048 + sw0);  \
      dst[j * 2 + 1] =                                                         \
          *(const bf16x8*)((buf) + brow + ((s)*2 + j) * 2048 + sw1);           \
    }                                                                          \
  }
#define QUAD(BV, I0, J0)                                                       \
  {                                                                            \
    __builtin_amdgcn_s_setprio(1);                                             \
    _Pragma("unroll") for (int i = 0; i < 4; ++i)                              \
        _Pragma("unroll") for (int j = 0; j < 2; ++j)                          \
            _Pragma("unroll") for (int kk = 0; kk < 2; ++kk)                   \
                acc[(I0) + i][(J0) + j] =                                      \
                    __builtin_amdgcn_mfma_f32_16x16x32_bf16(                   \
                        aS[i * 2 + kk], BV[j * 2 + kk],                        \
                        acc[(I0) + i][(J0) + j], 0, 0, 0);                     \
    __builtin_amdgcn_s_setprio(0);                                             \
  }
// One K-tile loop with compile-time quadrant start (SA,SB). Covers all four
// quadrants: (SA,SB),(SA,1-SB),(1-SA,1-SB),(1-SA,SB). Staging placement is
// identical across variants (by phase index), barrier count identical.
#define TILE_LOOP(SA, SB)                                                      \
  for (int T = 0; T < NT; ++T) {                                               \
    char* buf = lds + (T & 1) * 65536;                                         \
    const bool ST = (T < NT - 1);                                              \
    VMC(0);                                                                    \
    BARRIER();                                                                 \
    if (ST) STG_A(0, T + 1);                                                   \
    RD_A(buf, SA);                                                             \
    RD_B(bA, buf, SB);                                                         \
    LGK0();                                                                    \
    QUAD(bA, (SA) * 4, (SB) * 2);                                              \
    RD_B(bB, buf, 1 - (SB));                                                   \
    if (ST) STG_A(1, T + 1);                                                   \
    LGK0();                                                                    \
    QUAD(bB, (SA) * 4, (1 - (SB)) * 2);                                        \
    RD_A(buf, 1 - (SA));                                                       \
    if (ST) STG_B(0, T + 1);                                                   \
    LGK0();                                                                    \
    QUAD(bB, (1 - (SA)) * 4, (1 - (SB)) * 2);                                  \
    if (ST) STG_B(1, T + 1);                                                   \
    QUAD(bA, (1 - (SA)) * 4, (SB) * 2);                                        \
  }

  f32x4 acc[8][4] = {};
  bf16x8 aS[8], bA[4], bB[4];
  const int NT = K >> 6;  // >= 2

  STG_A(0, 0); STG_A(1, 0); STG_B(0, 0); STG_B(1, 0);

  if (wm == 0) {
    TILE_LOOP(0, 0);
  } else {
    TILE_LOOP(1, 1);
  }
#undef STG_A
#undef STG_B
#undef RD_A
#undef RD_B
#undef QUAD
#undef TILE_LOOP

#pragma unroll
  for (int i = 0; i < 8; ++i)
#pragma unroll
    for (int j = 0; j < 4; ++j)
#pragma unroll
      for (int r = 0; r < 4; ++r) {
        long gi = row0 + wm * 128 + i * 16 + fq * 4 + r;
        long gj = col0 + wn * 64 + j * 16 + fr;
        float v = acc[i][j][r];
        if (BIAS == 1) v += bias[gj];
        long idx = gi * (long)N + gj;
        if (EMASK) v *= __expf((float)ml[idx] - mrow[gi]) * invrow[gi];
        if (RES) v += res[idx];
        if (OUTBF16) outb[idx] = (bf16_t)v;
        else outf[idx] = v;
      }
}

// ============ 256-row x 128-col tile 8-wave GEMM, BK=64 ====================
// Grid (N/128, M/256), 256 blocks = exact fill for our shapes. Waves: 4Mx2N,
// per-wave 64x64 out. LDS: 2 x 48KB {A 256x128B, B 128x128B}. BIAS: 0 none,
// 2 per-row bias[gi].
template <int BIAS>
__global__ __launch_bounds__(512, 2) void gemmT128(
    const bf16_t* __restrict__ A, long lda, const bf16_t* __restrict__ B,
    long ldb, const float* __restrict__ bias, bf16_t* __restrict__ out,
    int M, int N, int K) {
  __shared__ __align__(1024) char lds[98304];
  const int tid = threadIdx.x;
  const int gx = N >> 7;
  int bid = blockIdx.y * gx + blockIdx.x;
  const int nwg = gridDim.x * gridDim.y;  // multiple of 8
  const int cpx = nwg >> 3;
  bid = (bid & 7) * cpx + (bid >> 3);     // XCD-aware bijective swizzle
  const long row0 = (long)(bid / gx) * 256;
  const long col0 = (long)(bid % gx) * 128;

  const int w = tid >> 6, lane = tid & 63;
  const int wm = w >> 1, wn = w & 1;      // 4M x 2N waves
  const int fr = lane & 15, fq = lane >> 4;

  const int arow = (wm * 64 + fr) * 128;
  const int brow = 32768 + (wn * 64 + fr) * 128;
  const int sw0 = ((fq ^ (fr & 7)) << 4);
  const int sw1 = (((4 | fq) ^ (fr & 7)) << 4);

  const int r0 = tid >> 3;
  const int s0 = (tid & 7) ^ (r0 & 7);
  const bf16_t* Ap = A + (row0 + r0) * lda + s0 * 8;
  const bf16_t* Bp = B + (col0 + r0) * ldb + s0 * 8;
  const int dstA = w * 1024;

#define STG_A(U)                                                               \
  {                                                                            \
    char* d_ = lds + (((U)&1) * 49152) + dstA;                                 \
    const bf16_t* s_ = Ap + (long)(U)*64;                                      \
    GLOAD16(s_, d_);                                                           \
    GLOAD16(s_ + 64 * lda, d_ + 8192);                                         \
    GLOAD16(s_ + 128 * lda, d_ + 16384);                                       \
    GLOAD16(s_ + 192 * lda, d_ + 24576);                                       \
  }
#define STG_B(U)                                                               \
  {                                                                            \
    char* d_ = lds + (((U)&1) * 49152) + 32768 + dstA;                         \
    const bf16_t* s_ = Bp + (long)(U)*64;                                      \
    GLOAD16(s_, d_);                                                           \
    GLOAD16(s_ + 64 * ldb, d_ + 8192);                                         \
  }
#define RD_A(buf)                                                              \
  {                                                                            \
    _Pragma("unroll") for (int i = 0; i < 4; ++i) {                            \
      aS[i * 2] = *(const bf16x8*)((buf) + arow + i * 2048 + sw0);             \
      aS[i * 2 + 1] = *(const bf16x8*)((buf) + arow + i * 2048 + sw1);         \
    }                                                                          \
  }
#define RD_B(dst, buf, s)                                                      \
  {                                                                            \
    _Pragma("unroll") for (int j = 0; j < 2; ++j) {                            \
      dst[j * 2] = *(const bf16x8*)((buf) + brow + ((s)*2 + j) * 2048 + sw0);  \
      dst[j * 2 + 1] =                                                         \
          *(const bf16x8*)((buf) + brow + ((s)*2 + j) * 2048 + sw1);           \
    }                                                                          \
  }
#define QUAD(BV, J0)                                                           \
  {                                                                            \
    __builtin_amdgcn_s_setprio(1);                                             \
    _Pragma("unroll") for (int i = 0; i < 4; ++i)                              \
        _Pragma("unroll") for (int j = 0; j < 2; ++j)                          \
            _Pragma("unroll") for (int kk = 0; kk < 2; ++kk)                   \
                acc[i][J0 + j] = __builtin_amdgcn_mfma_f32_16x16x32_bf16(      \
                    aS[i * 2 + kk], BV[j * 2 + kk], acc[i][J0 + j], 0, 0, 0);  \
    __builtin_amdgcn_s_setprio(0);                                             \
  }

  f32x4 acc[4][4] = {};
  bf16x8 aS[8], bA[4], bB[4];
  const int NT = K >> 6;  // >= 2

  STG_A(0); STG_B(0);

  for (int T = 0; T < NT; ++T) {
    char* buf = lds + (T & 1) * 49152;
    const bool ST = (T < NT - 1);
    VMC(0);
    BARRIER();
    if (ST) STG_A(T + 1);
    RD_A(buf);
    RD_B(bA, buf, 0);
    LGK0();
    QUAD(bA, 0);
    RD_B(bB, buf, 1);
    if (ST) STG_B(T + 1);
    LGK0();
    QUAD(bB, 2);
  }
#undef STG_A
#undef STG_B
#undef RD_A
#undef RD_B
#undef QUAD

#pragma unroll
  for (int i = 0; i < 4; ++i)
#pragma unroll
    for (int j = 0; j < 4; ++j)
#pragma unroll
      for (int r = 0; r < 4; ++r) {
        long gi = row0 + wm * 64 + i * 16 + fq * 4 + r;
        long gj = col0 + wn * 64 + j * 16 + fr;
        float v = acc[i][j][r];
        if (BIAS == 2) v += bias[gi];
        out[gi * (long)N + gj] = (bf16_t)v;
      }
}

// ------- row softmax stats over 8192 cols: write per-row max and 1/sum ----
__global__ __launch_bounds__(256) void softmax_stats(
    const bf16_t* __restrict__ buf, float* __restrict__ mrow,
    float* __restrict__ invrow) {
  const long row = blockIdx.x;
  const bf16_t* p = buf + row * 8192;
  const int t = threadIdx.x;
  float v[32];
#pragma unroll
  for (int i = 0; i < 4; i++) {
    bf16x8 raw = *(const bf16x8*)(p + t * 32 + i * 8);
#pragma unroll
    for (int j = 0; j < 8; j++) v[i * 8 + j] = (float)raw[j];
  }
  float m = -1e30f;
#pragma unroll
  for (int i = 0; i < 32; i++) m = fmaxf(m, v[i]);
  for (int off = 32; off; off >>= 1) m = fmaxf(m, __shfl_xor(m, off, 64));
  __shared__ float redm[4], reds[4];
  if ((t & 63) == 0) redm[t >> 6] = m;
  __syncthreads();
  m = fmaxf(fmaxf(redm[0], redm[1]), fmaxf(redm[2], redm[3]));
  float s = 0.f;
#pragma unroll
  for (int i = 0; i < 32; i++) s += __expf(v[i] - m);
  for (int off = 32; off; off >>= 1) s += __shfl_xor(s, off, 64);
  if ((t & 63) == 0) reds[t >> 6] = s;
  __syncthreads();
  if (t == 0) {
    s = reds[0] + reds[1] + reds[2] + reds[3];
    mrow[row] = m;
    invrow[row] = 1.0f / s;
  }
}

// --------- row softmax: bf16 logits in, fp32 out + bf16 in-place ----------
__global__ __launch_bounds__(256) void softmax_f_k(bf16_t* __restrict__ fm,
                                                   float* __restrict__ outf) {
  const long row = blockIdx.x;
  bf16_t* p = fm + row * 8192;
  float* q = outf + row * 8192;
  const int t = threadIdx.x;
  float v[32];
#pragma unroll
  for (int i = 0; i < 4; i++) {
    bf16x8 raw = *(const bf16x8*)(p + t * 32 + i * 8);
#pragma unroll
    for (int j = 0; j < 8; j++) v[i * 8 + j] = (float)raw[j];
  }
  float m = -1e30f;
#pragma unroll
  for (int i = 0; i < 32; i++) m = fmaxf(m, v[i]);
  for (int off = 32; off; off >>= 1) m = fmaxf(m, __shfl_xor(m, off, 64));
  __shared__ float redm[4], reds[4];
  if ((t & 63) == 0) redm[t >> 6] = m;
  __syncthreads();
  m = fmaxf(fmaxf(redm[0], redm[1]), fmaxf(redm[2], redm[3]));
  float s = 0.f;
#pragma unroll
  for (int i = 0; i < 32; i++) {
    v[i] = __expf(v[i] - m);
    s += v[i];
  }
  for (int off = 32; off; off >>= 1) s += __shfl_xor(s, off, 64);
  if ((t & 63) == 0) reds[t >> 6] = s;
  __syncthreads();
  s = reds[0] + reds[1] + reds[2] + reds[3];
  float inv = 1.0f / s;
#pragma unroll
  for (int i = 0; i < 8; i++) {
    float4 o;
    o.x = v[i * 4 + 0] * inv;
    o.y = v[i * 4 + 1] * inv;
    o.z = v[i * 4 + 2] * inv;
    o.w = v[i * 4 + 3] * inv;
    *(float4*)(q + t * 32 + i * 4) = o;
  }
#pragma unroll
  for (int i = 0; i < 4; i++) {
    bf16x8 o;
#pragma unroll
    for (int j = 0; j < 8; j++) o[j] = (bf16_t)(v[i * 8 + j] * inv);
    *(bf16x8*)(p + t * 32 + i * 8) = o;
  }
}

// ---------------------------------------------------------------------------
extern "C" void kernel_launch(void* const* d_in, const int* in_sizes, int n_in,
                              void* d_out, int out_size, void* d_ws,
                              size_t ws_size, hipStream_t stream) {
  const int N = 8192, C = 2048, IC = 1024;
  const float* x = (const float*)d_in[0];
  const float* theta_w = (const float*)d_in[1];
  const float* theta_b = (const float*)d_in[2];
  const float* phi_w = (const float*)d_in[3];
  const float* phi_b = (const float*)d_in[4];
  const float* g_w = (const float*)d_in[5];
  const float* g_b = (const float*)d_in[6];
  const float* W_w = (const float*)d_in[7];
  const float* W_b = (const float*)d_in[8];
  const float* mask_w = (const float*)d_in[9];
  const float* mask_b = (const float*)d_in[10];

  float* z_out = (float*)d_out;            // [N,C] fp32
  float* f_out = z_out + (long)N * C;      // [N,N] fp32

  bf16_t* ML = (bf16_t*)f_out;             // [N,N] bf16 raw mask logits
  bf16_t* thph16 = (bf16_t*)z_out;         // [N,2048]: theta | phi
  bf16_t* gT16 = thph16 + (long)N * 2048;  // [IC,N]

  char* w = (char*)d_ws;
  bf16_t* xb = (bf16_t*)w;      w += (long)N * C * 2;
  bf16_t* mwb = (bf16_t*)w;     w += (long)N * C * 2;
  bf16_t* thwb = (bf16_t*)w;    w += (long)IC * C * 2;
  bf16_t* phwb = (bf16_t*)w;    w += (long)IC * C * 2;
  bf16_t* gwb = (bf16_t*)w;     w += (long)IC * C * 2;
  bf16_t* Wwb = (bf16_t*)w;     w += (long)C * IC * 2;
  bf16_t* fm = (bf16_t*)w;      w += (long)N * N * 2;
  bf16_t* y16 = (bf16_t*)w;     w += (long)N * IC * 2;
  float* mrowb = (float*)w;     w += (long)N * 4;
  float* invrowb = (float*)w;   w += (long)N * 4;
  float* thph_b = (float*)w;    w += (long)2 * IC * 4;

  cast_all_k<<<4096, 256, 0, stream>>>(x, xb, mask_w, mwb, theta_w, thwb,
                                       phi_w, phwb, g_w, gwb, W_w, Wwb);
  hipMemcpyAsync(thph_b, theta_b, IC * 4, hipMemcpyDeviceToDevice, stream);
  hipMemcpyAsync(thph_b + IC, phi_b, IC * 4, hipMemcpyDeviceToDevice, stream);

  // theta+phi merged projection: [8192,2048] = xb @ [thwb;phwb]^T + bias
  gemm256<1, false, false, true><<<dim3(2048 / 256, N / 256), 512, 0, stream>>>(
      xb, C, thwb, C, thph_b, nullptr, nullptr, nullptr, nullptr, nullptr,
      thph16, N, 2048, C);
  // g_x^T : [IC,N] = g_w @ xb^T + g_b (row bias), 256x128-tile, 256 blocks
  gemmT128<2><<<dim3(N / 128, IC / 256), 512, 0, stream>>>(
      gwb, C, xb, C, g_b, gT16, IC, N, C);
  // mask logits -> raw ML (bias per col)
  gemm256<1, false, false, true><<<dim3(N / 256, N / 256), 512, 0, stream>>>(
      xb, C, mwb, C, mask_b, nullptr, nullptr, nullptr, nullptr, nullptr,
      ML, N, N, C);
  // mask softmax stats only (read-only pass)
  softmax_stats<<<N, 256, 0, stream>>>(ML, mrowb, invrowb);
  // f*mask logits: theta_x @ phi_x^T with folded exp-mask epilogue
  gemm256<0, true, false, true><<<dim3(N / 256, N / 256), 512, 0, stream>>>(
      thph16, 2048, thph16 + 1024, 2048, nullptr, ML, mrowb, invrowb,
      nullptr, nullptr, fm, N, N, IC);
  softmax_f_k<<<N, 256, 0, stream>>>(fm, f_out);
  // y = P @ g_x (NT via gT16), 256x128-tile kernel, exact 256-block fill
  gemmT128<0><<<dim3(IC / 128, N / 256), 512, 0, stream>>>(
      fm, N, gT16, N, nullptr, y16, N, IC, N);
  // z = y @ W_w^T + W_b + x (256^2 kernel, fp32 out + residual)
  gemm256<1, false, true, false><<<dim3(C / 256, N / 256), 512, 0, stream>>>(
      y16, IC, Wwb, IC, W_b, nullptr, nullptr, nullptr, x, z_out, nullptr,
      N, C, IC);
}

// Round 17
// 915.082 us; speedup vs baseline: 4.5553x; 1.0228x over previous
//
#include <hip/hip_runtime.h>
#include <hip/hip_bf16.h>

typedef __bf16 bf16_t;
typedef __bf16 bf16x8 __attribute__((ext_vector_type(8)));
typedef float f32x4 __attribute__((ext_vector_type(4)));

#define GLOAD16(gp, lp) __builtin_amdgcn_global_load_lds(                      \
    (const __attribute__((address_space(1))) void*)(gp),                       \
    (__attribute__((address_space(3))) void*)(lp), 16, 0, 0)
#define BARRIER() asm volatile("s_barrier" ::: "memory")
#define VMC(n) asm volatile("s_waitcnt vmcnt(" #n ")" ::: "memory")
#define LGK0()                                                                 \
  do {                                                                         \
    asm volatile("s_waitcnt lgkmcnt(0)" ::: "memory");                         \
    __builtin_amdgcn_sched_barrier(0);                                         \
  } while (0)

// -------- fused fp32 -> bf16 casts (6 segments) + bias concat, one launch --
__global__ __launch_bounds__(256) void cast_all_k(
    const float* __restrict__ x, bf16_t* __restrict__ xb,
    const float* __restrict__ mw, bf16_t* __restrict__ mwb,
    const float* __restrict__ tw, bf16_t* __restrict__ twb,
    const float* __restrict__ pw, bf16_t* __restrict__ pwb,
    const float* __restrict__ gw, bf16_t* __restrict__ gwb,
    const float* __restrict__ Ww, bf16_t* __restrict__ Wwb,
    const float* __restrict__ tb, const float* __restrict__ pb,
    float* __restrict__ thph_b) {
  const long NB = 2097152;   // 8192*2048/8
  const long WB = 262144;    // 1024*2048/8
  const long totm = 2 * NB + 4 * WB;
  const long total = totm + 256;  // + 2048/8 bias-concat slots
  long i = (long)blockIdx.x * blockDim.x + threadIdx.x;
  long stride = (long)gridDim.x * blockDim.x;
  for (; i < total; i += stride) {
    if (i >= totm) {  // bias concat: thph_b[0:1024]=tb, [1024:2048]=pb (fp32)
      long e = (i - totm) * 8;
      const float* src = (e < 1024) ? (tb + e) : (pb + e - 1024);
      float4 a = *(const float4*)(src);
      float4 b = *(const float4*)(src + 4);
      *(float4*)(thph_b + e) = a;
      *(float4*)(thph_b + e + 4) = b;
      continue;
    }
    const float* src;
    bf16_t* dst;
    long off;
    if (i < NB) {
      src = x; dst = xb; off = i;
    } else if (i < 2 * NB) {
      src = mw; dst = mwb; off = i - NB;
    } else {
      long j = i - 2 * NB;
      int seg = (int)(j >> 18);
      off = j & (WB - 1);
      src = (seg == 0) ? tw : (seg == 1) ? pw : (seg == 2) ? gw : Ww;
      dst = (seg == 0) ? twb : (seg == 1) ? pwb : (seg == 2) ? gwb : Wwb;
    }
    long e = off * 8;
    float4 a = *(const float4*)(src + e);
    float4 b = *(const float4*)(src + e + 4);
    bf16x8 o;
    o[0] = (__bf16)a.x; o[1] = (__bf16)a.y; o[2] = (__bf16)a.z; o[3] = (__bf16)a.w;
    o[4] = (__bf16)b.x; o[5] = (__bf16)b.y; o[6] = (__bf16)b.z; o[7] = (__bf16)b.w;
    *(bf16x8*)(dst + e) = o;
  }
}

// ============ 256x256-tile 8-wave GEMM, BK=64, 1 barrier / 1 vmcnt per
// K-tile, TWO 32-MFMA phases (merged from 4x16 to double the per-lgkm0 MFMA
// burst). LDS: 2 x 64KB buffers {A 256x128B, B 256x128B}. 16B slot ^= row&7;
// staging inverse-swizzles the global source (linear LDS dest).
template <int BIAS, bool EMASK, bool RES, bool OUTBF16>
__global__ __launch_bounds__(512, 2) void gemm256(
    const bf16_t* __restrict__ A, long lda, const bf16_t* __restrict__ B,
    long ldb, const float* __restrict__ bias, const bf16_t* __restrict__ ml,
    const float* __restrict__ mrow, const float* __restrict__ invrow,
    const float* __restrict__ res, float* __restrict__ outf,
    bf16_t* __restrict__ outb, int M, int N, int K) {
  __shared__ __align__(1024) char lds[131072];
  const int tid = threadIdx.x;
  const int gx = N >> 8;
  int bid = blockIdx.y * gx + blockIdx.x;
  const int nwg = gridDim.x * gridDim.y;  // multiple of 8 for our shapes
  const int cpx = nwg >> 3;
  bid = (bid & 7) * cpx + (bid >> 3);     // XCD-aware bijective swizzle
  const long row0 = (long)(bid / gx) * 256;
  const long col0 = (long)(bid % gx) * 256;

  const int w = tid >> 6, lane = tid & 63;
  const int wm = w >> 2, wn = w & 3;      // 2M x 4N waves
  const int fr = lane & 15, fq = lane >> 4;

  const int arow = (wm * 128 + fr) * 128;
  const int brow = 32768 + (wn * 64 + fr) * 128;
  const int sw0 = ((fq ^ (fr & 7)) << 4);
  const int sw1 = (((4 | fq) ^ (fr & 7)) << 4);

  const int r0 = tid >> 3;
  const int s0 = (tid & 7) ^ (r0 & 7);
  const bf16_t* Ap = A + (row0 + r0) * lda + s0 * 8;
  const bf16_t* Bp = B + (col0 + r0) * ldb + s0 * 8;
  const int dstA = w * 1024;

#define STG_A(h, U)                                                            \
  {                                                                            \
    const bf16_t* s_ = Ap + (long)(h)*128 * lda + (long)(U)*64;                \
    char* d_ = lds + (((U)&1) * 65536) + (h)*16384 + dstA;                     \
    GLOAD16(s_, d_);                                                           \
    GLOAD16(s_ + 64 * lda, d_ + 8192);                                         \
  }
#define STG_B(h, U)                                                            \
  {                                                                            \
    const bf16_t* s_ = Bp + (long)(h)*128 * ldb + (long)(U)*64;                \
    char* d_ = lds + (((U)&1) * 65536) + 32768 + (h)*16384 + dstA;             \
    GLOAD16(s_, d_);                                                           \
    GLOAD16(s_ + 64 * ldb, d_ + 8192);                                         \
  }
#define RD_A(buf, s)                                                           \
  {                                                                            \
    _Pragma("unroll") for (int i = 0; i < 4; ++i) {                            \
      aS[i * 2] = *(const bf16x8*)((buf) + arow + ((s)*4 + i) * 2048 + sw0);   \
      aS[i * 2 + 1] =                                                          \
          *(const bf16x8*)((buf) + arow + ((s)*4 + i) * 2048 + sw1);           \
    }                                                                          \
  }
#define RD_B(dst, buf, s)                                                      \
  {                                                                            \
    _Pragma("unroll") for (int j = 0; j < 2; ++j) {                            \
      dst[j * 2] = *(const bf16x8*)((buf) + brow + ((s)*2 + j) * 2048 + sw0);  \
      dst[j * 2 + 1] =                                                         \
          *(const bf16x8*)((buf) + brow + ((s)*2 + j) * 2048 + sw1);           \
    }                                                                          \
  }
#define QUAD(BV, I0, J0)                                                       \
  {                                                                            \
    __builtin_amdgcn_s_setprio(1);                                             \
    _Pragma("unroll") for (int i = 0; i < 4; ++i)                              \
        _Pragma("unroll") for (int j = 0; j < 2; ++j)                          \
            _Pragma("unroll") for (int kk = 0; kk < 2; ++kk)                   \
                acc[I0 + i][J0 + j] = __builtin_amdgcn_mfma_f32_16x16x32_bf16( \
                    aS[i * 2 + kk], BV[j * 2 + kk], acc[I0 + i][J0 + j], 0, 0, \
                    0);                                                        \
    __builtin_amdgcn_s_setprio(0);                                             \
  }

  f32x4 acc[8][4] = {};
  bf16x8 aS[8], bA[4], bB[4];
  const int NT = K >> 6;  // >= 2

  STG_A(0, 0); STG_A(1, 0); STG_B(0, 0); STG_B(1, 0);

  for (int T = 0; T < NT; ++T) {
    char* buf = lds + (T & 1) * 65536;
    const bool ST = (T < NT - 1);
    VMC(0);
    BARRIER();
    // phase 0: A-lo + all B (16 reads); stage A(T+1); 32 MFMA
    if (ST) { STG_A(0, T + 1); STG_A(1, T + 1); }
    RD_A(buf, 0);
    RD_B(bA, buf, 0);
    RD_B(bB, buf, 1);
    LGK0();
    QUAD(bA, 0, 0);
    QUAD(bB, 0, 2);
    // phase 1: A-hi (8 reads); stage B(T+1); 32 MFMA
    RD_A(buf, 1);
    if (ST) { STG_B(0, T + 1); STG_B(1, T + 1); }
    LGK0();
    QUAD(bB, 4, 2);
    QUAD(bA, 4, 0);
  }
#undef STG_A
#undef STG_B
#undef RD_A
#undef RD_B
#undef QUAD

#pragma unroll
  for (int i = 0; i < 8; ++i)
#pragma unroll
    for (int j = 0; j < 4; ++j)
#pragma unroll
      for (int r = 0; r < 4; ++r) {
        long gi = row0 + wm * 128 + i * 16 + fq * 4 + r;
        long gj = col0 + wn * 64 + j * 16 + fr;
        float v = acc[i][j][r];
        if (BIAS == 1) v += bias[gj];
        long idx = gi * (long)N + gj;
        if (EMASK) v *= __expf((float)ml[idx] - mrow[gi]) * invrow[gi];
        if (RES) v += res[idx];
        if (OUTBF16) outb[idx] = (bf16_t)v;
        else outf[idx] = v;
      }
}

// ============ 256-row x 128-col tile 8-wave GEMM, BK=64, ONE 32-MFMA phase =
// Grid (N/128, M/256), 256 blocks = exact fill. Waves: 4Mx2N, per-wave 64x64.
// LDS: 2 x 48KB {A 256x128B, B 128x128B}. BIAS: 0 none, 2 per-row bias[gi].
template <int BIAS>
__global__ __launch_bounds__(512, 2) void gemmT128(
    const bf16_t* __restrict__ A, long lda, const bf16_t* __restrict__ B,
    long ldb, const float* __restrict__ bias, bf16_t* __restrict__ out,
    int M, int N, int K) {
  __shared__ __align__(1024) char lds[98304];
  const int tid = threadIdx.x;
  const int gx = N >> 7;
  int bid = blockIdx.y * gx + blockIdx.x;
  const int nwg = gridDim.x * gridDim.y;  // multiple of 8
  const int cpx = nwg >> 3;
  bid = (bid & 7) * cpx + (bid >> 3);     // XCD-aware bijective swizzle
  const long row0 = (long)(bid / gx) * 256;
  const long col0 = (long)(bid % gx) * 128;

  const int w = tid >> 6, lane = tid & 63;
  const int wm = w >> 1, wn = w & 1;      // 4M x 2N waves
  const int fr = lane & 15, fq = lane >> 4;

  const int arow = (wm * 64 + fr) * 128;
  const int brow = 32768 + (wn * 64 + fr) * 128;
  const int sw0 = ((fq ^ (fr & 7)) << 4);
  const int sw1 = (((4 | fq) ^ (fr & 7)) << 4);

  const int r0 = tid >> 3;
  const int s0 = (tid & 7) ^ (r0 & 7);
  const bf16_t* Ap = A + (row0 + r0) * lda + s0 * 8;
  const bf16_t* Bp = B + (col0 + r0) * ldb + s0 * 8;
  const int dstA = w * 1024;

#define STG_A(U)                                                               \
  {                                                                            \
    char* d_ = lds + (((U)&1) * 49152) + dstA;                                 \
    const bf16_t* s_ = Ap + (long)(U)*64;                                      \
    GLOAD16(s_, d_);                                                           \
    GLOAD16(s_ + 64 * lda, d_ + 8192);                                         \
    GLOAD16(s_ + 128 * lda, d_ + 16384);                                       \
    GLOAD16(s_ + 192 * lda, d_ + 24576);                                       \
  }
#define STG_B(U)                                                               \
  {                                                                            \
    char* d_ = lds + (((U)&1) * 49152) + 32768 + dstA;                         \
    const bf16_t* s_ = Bp + (long)(U)*64;                                      \
    GLOAD16(s_, d_);                                                           \
    GLOAD16(s_ + 64 * ldb, d_ + 8192);                                         \
  }
#define RD_A(buf)                                                              \
  {                                                                            \
    _Pragma("unroll") for (int i = 0; i < 4; ++i) {                            \
      aS[i * 2] = *(const bf16x8*)((buf) + arow + i * 2048 + sw0);             \
      aS[i * 2 + 1] = *(const bf16x8*)((buf) + arow + i * 2048 + sw1);         \
    }                                                                          \
  }
#define RD_B(dst, buf, s)                                                      \
  {                                                                            \
    _Pragma("unroll") for (int j = 0; j < 2; ++j) {                            \
      dst[j * 2] = *(const bf16x8*)((buf) + brow + ((s)*2 + j) * 2048 + sw0);  \
      dst[j * 2 + 1] =                                                         \
          *(const bf16x8*)((buf) + brow + ((s)*2 + j) * 2048 + sw1);           \
    }                                                                          \
  }
#define QUAD(BV, J0)                                                           \
  {                                                                            \
    __builtin_amdgcn_s_setprio(1);                                             \
    _Pragma("unroll") for (int i = 0; i < 4; ++i)                              \
        _Pragma("unroll") for (int j = 0; j < 2; ++j)                          \
            _Pragma("unroll") for (int kk = 0; kk < 2; ++kk)                   \
                acc[i][J0 + j] = __builtin_amdgcn_mfma_f32_16x16x32_bf16(      \
                    aS[i * 2 + kk], BV[j * 2 + kk], acc[i][J0 + j], 0, 0, 0);  \
    __builtin_amdgcn_s_setprio(0);                                             \
  }

  f32x4 acc[4][4] = {};
  bf16x8 aS[8], bA[4], bB[4];
  const int NT = K >> 6;  // >= 2

  STG_A(0); STG_B(0);

  for (int T = 0; T < NT; ++T) {
    char* buf = lds + (T & 1) * 49152;
    const bool ST = (T < NT - 1);
    VMC(0);
    BARRIER();
    if (ST) STG_A(T + 1);
    RD_A(buf);
    RD_B(bA, buf, 0);
    RD_B(bB, buf, 1);
    if (ST) STG_B(T + 1);
    LGK0();
    QUAD(bA, 0);
    QUAD(bB, 2);
  }
#undef STG_A
#undef STG_B
#undef RD_A
#undef RD_B
#undef QUAD

#pragma unroll
  for (int i = 0; i < 4; ++i)
#pragma unroll
    for (int j = 0; j < 4; ++j)
#pragma unroll
      for (int r = 0; r < 4; ++r) {
        long gi = row0 + wm * 64 + i * 16 + fq * 4 + r;
        long gj = col0 + wn * 64 + j * 16 + fr;
        float v = acc[i][j][r];
        if (BIAS == 2) v += bias[gi];
        out[gi * (long)N + gj] = (bf16_t)v;
      }
}

// ------- row softmax stats over 8192 cols: write per-row max and 1/sum ----
__global__ __launch_bounds__(256) void softmax_stats(
    const bf16_t* __restrict__ buf, float* __restrict__ mrow,
    float* __restrict__ invrow) {
  const long row = blockIdx.x;
  const bf16_t* p = buf + row * 8192;
  const int t = threadIdx.x;
  float v[32];
#pragma unroll
  for (int i = 0; i < 4; i++) {
    bf16x8 raw = *(const bf16x8*)(p + t * 32 + i * 8);
#pragma unroll
    for (int j = 0; j < 8; j++) v[i * 8 + j] = (float)raw[j];
  }
  float m = -1e30f;
#pragma unroll
  for (int i = 0; i < 32; i++) m = fmaxf(m, v[i]);
  for (int off = 32; off; off >>= 1) m = fmaxf(m, __shfl_xor(m, off, 64));
  __shared__ float redm[4], reds[4];
  if ((t & 63) == 0) redm[t >> 6] = m;
  __syncthreads();
  m = fmaxf(fmaxf(redm[0], redm[1]), fmaxf(redm[2], redm[3]));
  float s = 0.f;
#pragma unroll
  for (int i = 0; i < 32; i++) s += __expf(v[i] - m);
  for (int off = 32; off; off >>= 1) s += __shfl_xor(s, off, 64);
  if ((t & 63) == 0) reds[t >> 6] = s;
  __syncthreads();
  if (t == 0) {
    s = reds[0] + reds[1] + reds[2] + reds[3];
    mrow[row] = m;
    invrow[row] = 1.0f / s;
  }
}

// --------- row softmax: bf16 logits in, fp32 out + bf16 in-place ----------
__global__ __launch_bounds__(256) void softmax_f_k(bf16_t* __restrict__ fm,
                                                   float* __restrict__ outf) {
  const long row = blockIdx.x;
  bf16_t* p = fm + row * 8192;
  float* q = outf + row * 8192;
  const int t = threadIdx.x;
  float v[32];
#pragma unroll
  for (int i = 0; i < 4; i++) {
    bf16x8 raw = *(const bf16x8*)(p + t * 32 + i * 8);
#pragma unroll
    for (int j = 0; j < 8; j++) v[i * 8 + j] = (float)raw[j];
  }
  float m = -1e30f;
#pragma unroll
  for (int i = 0; i < 32; i++) m = fmaxf(m, v[i]);
  for (int off = 32; off; off >>= 1) m = fmaxf(m, __shfl_xor(m, off, 64));
  __shared__ float redm[4], reds[4];
  if ((t & 63) == 0) redm[t >> 6] = m;
  __syncthreads();
  m = fmaxf(fmaxf(redm[0], redm[1]), fmaxf(redm[2], redm[3]));
  float s = 0.f;
#pragma unroll
  for (int i = 0; i < 32; i++) {
    v[i] = __expf(v[i] - m);
    s += v[i];
  }
  for (int off = 32; off; off >>= 1) s += __shfl_xor(s, off, 64);
  if ((t & 63) == 0) reds[t >> 6] = s;
  __syncthreads();
  s = reds[0] + reds[1] + reds[2] + reds[3];
  float inv = 1.0f / s;
#pragma unroll
  for (int i = 0; i < 8; i++) {
    float4 o;
    o.x = v[i * 4 + 0] * inv;
    o.y = v[i * 4 + 1] * inv;
    o.z = v[i * 4 + 2] * inv;
    o.w = v[i * 4 + 3] * inv;
    *(float4*)(q + t * 32 + i * 4) = o;
  }
#pragma unroll
  for (int i = 0; i < 4; i++) {
    bf16x8 o;
#pragma unroll
    for (int j = 0; j < 8; j++) o[j] = (bf16_t)(v[i * 8 + j] * inv);
    *(bf16x8*)(p + t * 32 + i * 8) = o;
  }
}

// ---------------------------------------------------------------------------
extern "C" void kernel_launch(void* const* d_in, const int* in_sizes, int n_in,
                              void* d_out, int out_size, void* d_ws,
                              size_t ws_size, hipStream_t stream) {
  const int N = 8192, C = 2048, IC = 1024;
  const float* x = (const float*)d_in[0];
  const float* theta_w = (const float*)d_in[1];
  const float* theta_b = (const float*)d_in[2];
  const float* phi_w = (const float*)d_in[3];
  const float* phi_b = (const float*)d_in[4];
  const float* g_w = (const float*)d_in[5];
  const float* g_b = (const float*)d_in[6];
  const float* W_w = (const float*)d_in[7];
  const float* W_b = (const float*)d_in[8];
  const float* mask_w = (const float*)d_in[9];
  const float* mask_b = (const float*)d_in[10];

  float* z_out = (float*)d_out;            // [N,C] fp32
  float* f_out = z_out + (long)N * C;      // [N,N] fp32

  bf16_t* ML = (bf16_t*)f_out;             // [N,N] bf16 raw mask logits
  bf16_t* thph16 = (bf16_t*)z_out;         // [N,2048]: theta | phi
  bf16_t* gT16 = thph16 + (long)N * 2048;  // [IC,N]

  char* w = (char*)d_ws;
  bf16_t* xb = (bf16_t*)w;      w += (long)N * C * 2;
  bf16_t* mwb = (bf16_t*)w;     w += (long)N * C * 2;
  bf16_t* thwb = (bf16_t*)w;    w += (long)IC * C * 2;
  bf16_t* phwb = (bf16_t*)w;    w += (long)IC * C * 2;
  bf16_t* gwb = (bf16_t*)w;     w += (long)IC * C * 2;
  bf16_t* Wwb = (bf16_t*)w;     w += (long)C * IC * 2;
  bf16_t* fm = (bf16_t*)w;      w += (long)N * N * 2;
  bf16_t* y16 = (bf16_t*)w;     w += (long)N * IC * 2;
  float* mrowb = (float*)w;     w += (long)N * 4;
  float* invrowb = (float*)w;   w += (long)N * 4;
  float* thph_b = (float*)w;    w += (long)2 * IC * 4;

  cast_all_k<<<4096, 256, 0, stream>>>(x, xb, mask_w, mwb, theta_w, thwb,
                                       phi_w, phwb, g_w, gwb, W_w, Wwb,
                                       theta_b, phi_b, thph_b);

  // theta+phi merged projection: [8192,2048] = xb @ [thwb;phwb]^T + bias
  gemm256<1, false, false, true><<<dim3(2048 / 256, N / 256), 512, 0, stream>>>(
      xb, C, thwb, C, thph_b, nullptr, nullptr, nullptr, nullptr, nullptr,
      thph16, N, 2048, C);
  // g_x^T : [IC,N] = g_w @ xb^T + g_b (row bias), 256x128-tile, 256 blocks
  gemmT128<2><<<dim3(N / 128, IC / 256), 512, 0, stream>>>(
      gwb, C, xb, C, g_b, gT16, IC, N, C);
  // mask logits -> raw ML (bias per col)
  gemm256<1, false, false, true><<<dim3(N / 256, N / 256), 512, 0, stream>>>(
      xb, C, mwb, C, mask_b, nullptr, nullptr, nullptr, nullptr, nullptr,
      ML, N, N, C);
  // mask softmax stats only (read-only pass)
  softmax_stats<<<N, 256, 0, stream>>>(ML, mrowb, invrowb);
  // f*mask logits: theta_x @ phi_x^T with folded exp-mask epilogue
  gemm256<0, true, false, true><<<dim3(N / 256, N / 256), 512, 0, stream>>>(
      thph16, 2048, thph16 + 1024, 2048, nullptr, ML, mrowb, invrowb,
      nullptr, nullptr, fm, N, N, IC);
  softmax_f_k<<<N, 256, 0, stream>>>(fm, f_out);
  // y = P @ g_x (NT via gT16), 256x128-tile kernel, exact 256-block fill
  gemmT128<0><<<dim3(IC / 128, N / 256), 512, 0, stream>>>(
      fm, N, gT16, N, nullptr, y16, N, IC, N);
  // z = y @ W_w^T + W_b + x (256^2 kernel, fp32 out + residual)
  gemm256<1, false, true, false><<<dim3(C / 256, N / 256), 512, 0, stream>>>(
      y16, IC, Wwb, IC, W_b, nullptr, nullptr, nullptr, x, z_out, nullptr,
      N, C, IC);
}